// Round 11
// baseline (107.816 us; speedup 1.0000x reference)
//
#include <hip/hip_runtime.h>

// Modulated deformable conv2d, fp32 in/out, bf16 MFMA core.
// B=4, C=64, H=W=128, O=64, K=3x3, stride=1, pad=1, dil=1, og=1, groups=1.
//
// Round 16: K-split wave pairs inside r11's LDS-window structure. Main was
// latency-bound (resource floor ~6 us vs ~28 us observed; 4 waves/SIMD).
// Block = 512 thr / 8 waves; each 16-px strip owned by a wave PAIR:
// wave q in {0,1} handles channels q*32..q*32+31 -> per-tap chain halves
// (4 ds_read_b128, 64 blend FMA, 4 MFMA) and occupancy doubles to 8
// waves/SIMD (4 blocks/CU x 512 = 2048 thr exactly). Pair reduction reuses
// V's 32 KB after a barrier (16 KB partials) so LDS stays 32 KB.
// __launch_bounds__(512,8) caps VGPR at 64 (est. ~58). Prep = r15 verbatim.
// Fragment layouts (m89/m120-verified): A[m=lane&15][k=quad*8+j],
// B[k=quad*8+j][n=lane&15], D[row=quad*4+reg][col=lane&15].

#define BB 4
#define CC 64
#define HH 128
#define WW 128
#define OO 64
#define KHW 3
#define KK 9
#define HW (HH * WW)

typedef __bf16 bf16_t;
typedef bf16_t bf16x8 __attribute__((ext_vector_type(8)));
typedef float f32x4 __attribute__((ext_vector_type(4)));

// ---- prep: x (NCHW fp32) -> xt (NHWC bf16)  +  weight -> B-fragment bf16 ----
// blocks [0, BB*256): transpose; blocks [BB*256, +144): weight repack.
__global__ __launch_bounds__(256) void prep_kernel(const float* __restrict__ x,
                                                   bf16_t* __restrict__ xt,
                                                   const float* __restrict__ w,
                                                   bf16_t* __restrict__ wf) {
    __shared__ float tile[64 * 65];
    const int t = threadIdx.x;
    if (blockIdx.x < BB * 256) {
        const int b  = blockIdx.x >> 8;
        const int p0 = (blockIdx.x & 255) << 6;
#pragma unroll
        for (int i = 0; i < 16; ++i) {
            int c = i * 4 + (t >> 6);
            int p = t & 63;
            tile[c * 65 + p] = x[(b * CC + c) * HW + p0 + p];  // coalesced
        }
        __syncthreads();
        // store: thread t -> pixel p = t>>2, chunks q and q+4 (q = t&3).
        const int p = t >> 2;
        const int q = t & 3;
        bf16x8 v0, v1;
#pragma unroll
        for (int e = 0; e < 8; ++e) v0[e] = (bf16_t)tile[(q * 8 + e) * 65 + p];
#pragma unroll
        for (int e = 0; e < 8; ++e)
            v1[e] = (bf16_t)tile[((q + 4) * 8 + e) * 65 + p];
        bf16_t* dst = xt + (size_t)((b * HW) + p0 + p) * CC;
        *(bf16x8*)(dst + q * 8) = v0;
        *(bf16x8*)(dst + (q + 4) * 8) = v1;
    } else {
        // wf element index: ((tap*2+q)*4+nt)*64*8 + lane*8 + j
        //   holds W[o = nt*16 + (lane&15)][c = q*32 + (lane>>4)*8 + j][tap]
        int i = (blockIdx.x - BB * 256) * 256 + t;
        if (i >= OO * CC * KK) return;
        int j    = i & 7;
        int lane = (i >> 3) & 63;
        int nt   = (i >> 9) & 3;
        int q    = (i >> 11) & 1;
        int k    = i >> 12;
        int o = nt * 16 + (lane & 15);
        int c = q * 32 + ((lane >> 4) << 3) + j;
        wf[i] = (bf16_t)w[(o * CC + c) * KK + k];
    }
}

__global__ __launch_bounds__(512, 8) void deform_conv_mfma(
    const bf16_t* __restrict__ xt, const float* __restrict__ offset,
    const float* __restrict__ mask, const bf16x8* __restrict__ wf,
    const float* __restrict__ bias, float* __restrict__ out) {
    const int t     = threadIdx.x;
    // XCD-aware bijective swizzle: grid = 1024 = 8 * 128.
    const int wg    = (blockIdx.x & 7) * ((BB * 256) >> 3) + (blockIdx.x >> 3);
    const int b     = wg >> 8;
    const int ti    = wg & 255;                // tile id: 16x16 tiles of 8x8
    const int r0    = ((ti >> 4) << 3);        // tile top row
    const int c0    = ((ti & 15) << 3);        // tile left col
    const int lane  = t & 63;
    const int wv    = t >> 6;                  // 0..7
    const int strip = wv >> 1;                 // 0..3: 16-px strip (2 rows)
    const int q     = wv & 1;                  // K-half: ch q*32..q*32+31
    const int col   = lane & 15;               // A-row m == pixel in strip
    const int quad  = lane >> 4;
    const int prow  = r0 + 2 * strip + (col >> 3);
    const int pcol  = c0 + (col & 7);
    const int rem   = prow * WW + pcol;
    const int wy0   = r0 - 4;                  // window origin (16x16 px)
    const int wx0   = c0 - 4;
    const int cb    = q * 32 + (quad << 3);    // lane's 8-ch slot base
    const int ck    = (q << 2) + quad;         // lane's 16B chunk index 0..7

    __shared__ bf16_t V[256 * 64];             // 32 KB window, then partials

    const bf16_t* xb  = xt + (size_t)b * HW * CC;
    const float* offp = offset + (size_t)b * (2 * KK) * HW + rem;
    const float* mp   = mask + (size_t)b * KK * HW + rem;

    // ---- stage 16x16-px window: 512 thr, each half a pixel (4 chunks) ----
    {
        const int px   = t >> 1;               // window pixel 0..255
        const int half = t & 1;                // chunk group 0..3 / 4..7
        const int i  = px >> 4;                // window row
        const int j  = px & 15;                // window col
        const int cy = min(max(wy0 + i, 0), HH - 1);
        const int cx = min(max(wx0 + j, 0), WW - 1);
        const bf16_t* src = xb + (size_t)(cy * WW + cx) * CC + half * 32;
        bf16_t* dst = &V[px * 64];
        const int key = j & 7;
#pragma unroll
        for (int s = 0; s < 4; ++s) {
            int chunk = half * 4 + s;
            *(bf16x8*)(dst + (((chunk ^ key)) << 3)) =
                *(const bf16x8*)(src + s * 8);
        }
    }
    __syncthreads();

    f32x4 acc[4];
#pragma unroll
    for (int nt = 0; nt < 4; ++nt) acc[nt] = (f32x4){0.f, 0.f, 0.f, 0.f};

    float offy = offp[0];
    float offx = offp[HW];
    float mm   = mp[0];

#pragma unroll
    for (int k = 0; k < KK; ++k) {
        float n_offy = 0.f, n_offx = 0.f, n_mm = 0.f;
        if (k < KK - 1) {
            n_offy = offp[(2 * k + 2) * HW];
            n_offx = offp[(2 * k + 3) * HW];
            n_mm   = mp[(k + 1) * HW];
        }

        // ---- bilinear setup (exact reference semantics) ----
        float py = offy + (float)(k / KHW) + (float)(prow - 1);
        float px = offx + (float)(k % KHW) + (float)(pcol - 1);
        float fy0 = floorf(py), fx0 = floorf(px);
        float ly = py - fy0, lx = px - fx0;
        int y0 = (int)fy0, x0 = (int)fx0;
        int y1 = y0 + 1, x1 = x0 + 1;
        bool vy0 = (y0 >= 0) && (y0 < HH), vy1 = (y1 >= 0) && (y1 < HH);
        bool vx0 = (x0 >= 0) && (x0 < WW), vx1 = (x1 >= 0) && (x1 < WW);
        int cy0 = min(max(y0, 0), HH - 1), cy1 = min(max(y1, 0), HH - 1);
        int cx0 = min(max(x0, 0), WW - 1), cx1 = min(max(x1, 0), WW - 1);
        float w0 = (vy0 && vx0) ? mm * (1.0f - ly) * (1.0f - lx) : 0.0f;
        float w1 = (vy0 && vx1) ? mm * (1.0f - ly) * lx : 0.0f;
        float w2 = (vy1 && vx0) ? mm * ly * (1.0f - lx) : 0.0f;
        float w3 = (vy1 && vx1) ? mm * ly * lx : 0.0f;

        // ---- window-relative corner coords ----
        int uy0 = y0 - wy0, ux0 = x0 - wx0;
        int uy1 = uy0 + 1,  ux1 = ux0 + 1;
        bool iy0 = (unsigned)uy0 < 16u, iy1 = (unsigned)uy1 < 16u;
        bool ix0 = (unsigned)ux0 < 16u, ix1 = (unsigned)ux1 < 16u;
        int qy0 = min(max(uy0, 0), 15), qy1 = min(max(uy1, 0), 15);
        int qx0 = min(max(ux0, 0), 15), qx1 = min(max(ux1, 0), 15);
        int pa = (qy0 * 16 + qx0) * 64, pb = (qy0 * 16 + qx1) * 64;
        int pc = (qy1 * 16 + qx0) * 64, pd = (qy1 * 16 + qx1) * 64;
        int sa = (qx0 & 7), sb = (qx1 & 7);  // swizzle keys (row-indep)

        // ---- LDS gathers: this wave's 8-ch chunk only ----
        bf16x8 g00 = *(const bf16x8*)&V[pa + ((ck ^ sa) << 3)];
        bf16x8 g01 = *(const bf16x8*)&V[pb + ((ck ^ sb) << 3)];
        bf16x8 g10 = *(const bf16x8*)&V[pc + ((ck ^ sa) << 3)];
        bf16x8 g11 = *(const bf16x8*)&V[pd + ((ck ^ sb) << 3)];

        // ---- rare out-of-window fallback (exec-masked, usually skipped) ----
        if (w0 != 0.0f && !(iy0 && ix0))
            g00 = *(const bf16x8*)(xb + (size_t)(cy0 * WW + cx0) * CC + cb);
        if (w1 != 0.0f && !(iy0 && ix1))
            g01 = *(const bf16x8*)(xb + (size_t)(cy0 * WW + cx1) * CC + cb);
        if (w2 != 0.0f && !(iy1 && ix0))
            g10 = *(const bf16x8*)(xb + (size_t)(cy1 * WW + cx0) * CC + cb);
        if (w3 != 0.0f && !(iy1 && ix1))
            g11 = *(const bf16x8*)(xb + (size_t)(cy1 * WW + cx1) * CC + cb);

        // ---- blend -> A fragment (this wave's K=32 half) ----
        bf16x8 af;
#pragma unroll
        for (int i = 0; i < 8; ++i) {
            float v = w0 * (float)g00[i] + w1 * (float)g01[i] +
                      w2 * (float)g10[i] + w3 * (float)g11[i];
            af[i] = (bf16_t)v;
        }

        // ---- MFMA: 16 pixels x 64 outputs, this wave's K=32 half ----
#pragma unroll
        for (int nt = 0; nt < 4; ++nt) {
            bf16x8 bfg = wf[((k * 2 + q) * 4 + nt) * 64 + lane];
            acc[nt] = __builtin_amdgcn_mfma_f32_16x16x32_bf16(
                af, bfg, acc[nt], 0, 0, 0);
        }

        offy = n_offy;
        offx = n_offx;
        mm   = n_mm;
    }

    // ---- pair reduction: reuse V (32 KB) for q==1 partials (16 KB) ----
    __syncthreads();                           // all window reads done
    f32x4* R = (f32x4*)V;                      // [pair(4)][lane(64)][nt(4)]
    if (q) {
#pragma unroll
        for (int nt = 0; nt < 4; ++nt) R[(strip * 64 + lane) * 4 + nt] = acc[nt];
    }
    __syncthreads();
    if (!q) {
        // ---- epilogue: D[row=quad*4+reg][col]; row -> pixel, col -> out ----
#pragma unroll
        for (int nt = 0; nt < 4; ++nt) {
            int o = nt * 16 + col;
            float bv = bias[o];
            f32x4 r = acc[nt] + R[(strip * 64 + lane) * 4 + nt];
            r.x += bv; r.y += bv; r.z += bv; r.w += bv;
            float* dst = out + (size_t)(b * OO + o) * HW +
                         (r0 + 2 * strip + (quad >> 1)) * WW + c0 +
                         (quad & 1) * 4;
            *(f32x4*)dst = r;  // 4 consecutive pixels, 16B aligned
        }
    }
}

extern "C" void kernel_launch(void* const* d_in, const int* in_sizes, int n_in,
                              void* d_out, int out_size, void* d_ws,
                              size_t ws_size, hipStream_t stream) {
    const float* x      = (const float*)d_in[0];
    const float* offset = (const float*)d_in[1];
    const float* mask   = (const float*)d_in[2];
    const float* weight = (const float*)d_in[3];
    const float* bias   = (const float*)d_in[4];
    float* out = (float*)d_out;

    bf16_t* xt  = (bf16_t*)d_ws;                       // 4*16384*64*2 = 8 MB
    bf16_t* wfr = (bf16_t*)((char*)d_ws + (size_t)BB * HW * CC * 2);  // 72 KB

    int nwf_blocks = (OO * CC * KK + 255) / 256;       // 144
    prep_kernel<<<BB * 256 + nwf_blocks, 256, 0, stream>>>(x, xt, weight, wfr);

    deform_conv_mfma<<<BB * (HW / 64), 512, 0, stream>>>(
        xt, offset, mask, (const bf16x8*)wfr, bias, out);
}

// Round 12
// 103.634 us; speedup vs baseline: 1.0403x; 1.0403x over previous
//
#include <hip/hip_runtime.h>

// Modulated deformable conv2d, fp32 in/out, bf16 MFMA core.
// B=4, C=64, H=W=128, O=64, K=3x3, stride=1, pad=1, dil=1, og=1, groups=1.
//
// Round 17: r16's K-split regressed (occupancy is not the lever; barrier +
// LDS reduction cost ~5 us). Back to r15 structure. New: the main loop is a
// 2-tap software pipeline with NAMED parity register sets (r10's proven
// pattern) + __builtin_amdgcn_sched_barrier(0) to stop the compiler from
// sinking next-tap ds_reads below the current blend (r12 evidence: VGPR=52
// means the compiler serialized the tap chain, exposing ~120cyc LDS latency
// + setup chain 9x per wave). BODY(k): ISSUE(k+1 -> other set, incl early
// fallback globals) -> roll scalars k+2 -> sched_barrier(0) -> BLEND(k) ->
// 8 MFMA. Prep/staging/fallback/epilogue identical to r15.
// Fragment layouts (m89/m120-verified): A[m=lane&15][k=quad*8+j],
// B[k=quad*8+j][n=lane&15], D[row=quad*4+reg][col=lane&15].

#define BB 4
#define CC 64
#define HH 128
#define WW 128
#define OO 64
#define KHW 3
#define KK 9
#define HW (HH * WW)

typedef __bf16 bf16_t;
typedef bf16_t bf16x8 __attribute__((ext_vector_type(8)));
typedef float f32x4 __attribute__((ext_vector_type(4)));

// ---- prep: x (NCHW fp32) -> xt (NHWC bf16)  +  weight -> B-fragment bf16 ----
// blocks [0, BB*256): transpose; blocks [BB*256, +144): weight repack.
__global__ __launch_bounds__(256) void prep_kernel(const float* __restrict__ x,
                                                   bf16_t* __restrict__ xt,
                                                   const float* __restrict__ w,
                                                   bf16_t* __restrict__ wf) {
    __shared__ float tile[64 * 65];
    const int t = threadIdx.x;
    if (blockIdx.x < BB * 256) {
        const int b  = blockIdx.x >> 8;
        const int p0 = (blockIdx.x & 255) << 6;
#pragma unroll
        for (int i = 0; i < 16; ++i) {
            int c = i * 4 + (t >> 6);
            int p = t & 63;
            tile[c * 65 + p] = x[(b * CC + c) * HW + p0 + p];  // coalesced
        }
        __syncthreads();
        // store: thread t -> pixel p = t>>2, chunks q and q+4 (q = t&3).
        const int p = t >> 2;
        const int q = t & 3;
        bf16x8 v0, v1;
#pragma unroll
        for (int e = 0; e < 8; ++e) v0[e] = (bf16_t)tile[(q * 8 + e) * 65 + p];
#pragma unroll
        for (int e = 0; e < 8; ++e)
            v1[e] = (bf16_t)tile[((q + 4) * 8 + e) * 65 + p];
        bf16_t* dst = xt + (size_t)((b * HW) + p0 + p) * CC;
        *(bf16x8*)(dst + q * 8) = v0;
        *(bf16x8*)(dst + (q + 4) * 8) = v1;
    } else {
        // wf element index: ((tap*2+q)*4+nt)*64*8 + lane*8 + j
        //   holds W[o = nt*16 + (lane&15)][c = q*32 + (lane>>4)*8 + j][tap]
        int i = (blockIdx.x - BB * 256) * 256 + t;
        if (i >= OO * CC * KK) return;
        int j    = i & 7;
        int lane = (i >> 3) & 63;
        int nt   = (i >> 9) & 3;
        int q    = (i >> 11) & 1;
        int k    = i >> 12;
        int o = nt * 16 + (lane & 15);
        int c = q * 32 + ((lane >> 4) << 3) + j;
        wf[i] = (bf16_t)w[(o * CC + c) * KK + k];
    }
}

__global__ __launch_bounds__(256, 4) void deform_conv_mfma(
    const bf16_t* __restrict__ xt, const float* __restrict__ offset,
    const float* __restrict__ mask, const bf16x8* __restrict__ wf,
    const float* __restrict__ bias, float* __restrict__ out) {
    const int t    = threadIdx.x;
    // XCD-aware bijective swizzle: grid = 1024 = 8 * 128.
    const int wg   = (blockIdx.x & 7) * ((BB * 256) >> 3) + (blockIdx.x >> 3);
    const int b    = wg >> 8;
    const int ti   = wg & 255;                 // tile id: 16x16 tiles of 8x8
    const int r0   = ((ti >> 4) << 3);         // tile top row
    const int c0   = ((ti & 15) << 3);         // tile left col
    const int lane = t & 63;
    const int wv   = t >> 6;                   // wave: rows 2wv, 2wv+1
    const int col  = lane & 15;                // A-row m == pixel in wave
    const int quad = lane >> 4;
    const int prow = r0 + 2 * wv + (col >> 3); // this lane's pixel row
    const int pcol = c0 + (col & 7);
    const int rem  = prow * WW + pcol;
    const int wy0  = r0 - 4;                   // window origin (16x16 px)
    const int wx0  = c0 - 4;
    const int cb   = quad << 3;                // lane's 8-ch slot base

    __shared__ bf16_t V[256 * 64];             // 32 KB swizzled window

    const bf16_t* xb  = xt + (size_t)b * HW * CC;
    const float* offp = offset + (size_t)b * (2 * KK) * HW + rem;
    const float* mp   = mask + (size_t)b * KK * HW + rem;

    // ---- stage 16x16-pixel window, clamped, chunk-swizzled ----
    {
        const int i  = t >> 4;                 // window row 0..15
        const int j  = t & 15;                 // window col 0..15
        const int cy = min(max(wy0 + i, 0), HH - 1);
        const int cx = min(max(wx0 + j, 0), WW - 1);
        const bf16_t* src = xb + (size_t)(cy * WW + cx) * CC;
        bf16_t* dst = &V[(i * 16 + j) * 64];
        const int sw = (j & 7) * 8;
#pragma unroll
        for (int s = 0; s < 8; ++s)
            *(bf16x8*)(dst + ((s * 8) ^ sw)) = *(const bf16x8*)(src + s * 8);
    }
    __syncthreads();

    f32x4 acc[4];
#pragma unroll
    for (int nt = 0; nt < 4; ++nt) acc[nt] = (f32x4){0.f, 0.f, 0.f, 0.f};

    // ---- named 2-tap pipeline state ----
    float syA, sxA, smA, syB, sxB, smB;
    float wA0, wA1, wA2, wA3, wB0, wB1, wB2, wB3;
    bf16x8 gA00, gA01, gA10, gA11, hA00, hA01, hA10, hA11;
    bf16x8 gB00, gB01, gB10, gB11, hB00, hB01, hB10, hB11;
    bf16x8 af0, af1;

#define LOADS(k_, P_)                                                         \
    if ((k_) < KK) {                                                          \
        sy##P_ = offp[(2 * (k_)) * HW];                                       \
        sx##P_ = offp[(2 * (k_) + 1) * HW];                                   \
        sm##P_ = mp[(k_) * HW];                                               \
    }

#define ISSUE(k_, P_)                                                         \
    {                                                                         \
        float py = sy##P_ + (float)((k_) / KHW) + (float)(prow - 1);          \
        float px = sx##P_ + (float)((k_) % KHW) + (float)(pcol - 1);          \
        float fy0 = floorf(py), fx0 = floorf(px);                             \
        float ly = py - fy0, lx = px - fx0;                                   \
        int y0 = (int)fy0, x0 = (int)fx0;                                     \
        int y1 = y0 + 1, x1 = x0 + 1;                                         \
        bool vy0 = (y0 >= 0) && (y0 < HH), vy1 = (y1 >= 0) && (y1 < HH);      \
        bool vx0 = (x0 >= 0) && (x0 < WW), vx1 = (x1 >= 0) && (x1 < WW);      \
        int cy0 = min(max(y0, 0), HH - 1), cy1 = min(max(y1, 0), HH - 1);     \
        int cx0 = min(max(x0, 0), WW - 1), cx1 = min(max(x1, 0), WW - 1);     \
        float mmv = sm##P_;                                                   \
        w##P_##0 = (vy0 && vx0) ? mmv * (1.0f - ly) * (1.0f - lx) : 0.0f;     \
        w##P_##1 = (vy0 && vx1) ? mmv * (1.0f - ly) * lx : 0.0f;              \
        w##P_##2 = (vy1 && vx0) ? mmv * ly * (1.0f - lx) : 0.0f;              \
        w##P_##3 = (vy1 && vx1) ? mmv * ly * lx : 0.0f;                       \
        int uy0 = y0 - wy0, ux0 = x0 - wx0;                                   \
        int uy1 = uy0 + 1, ux1 = ux0 + 1;                                     \
        bool iy0 = (unsigned)uy0 < 16u, iy1 = (unsigned)uy1 < 16u;            \
        bool ix0 = (unsigned)ux0 < 16u, ix1 = (unsigned)ux1 < 16u;            \
        int qy0 = min(max(uy0, 0), 15), qy1 = min(max(uy1, 0), 15);           \
        int qx0 = min(max(ux0, 0), 15), qx1 = min(max(ux1, 0), 15);           \
        int pa = (qy0 * 16 + qx0) * 64, pb = (qy0 * 16 + qx1) * 64;           \
        int pc = (qy1 * 16 + qx0) * 64, pd = (qy1 * 16 + qx1) * 64;           \
        int sa = (qx0 & 7), sb = (qx1 & 7);                                   \
        g##P_##00 = *(const bf16x8*)&V[pa + ((quad ^ sa) << 3)];              \
        h##P_##00 = *(const bf16x8*)&V[pa + (((4 + quad) ^ sa) << 3)];        \
        g##P_##01 = *(const bf16x8*)&V[pb + ((quad ^ sb) << 3)];              \
        h##P_##01 = *(const bf16x8*)&V[pb + (((4 + quad) ^ sb) << 3)];        \
        g##P_##10 = *(const bf16x8*)&V[pc + ((quad ^ sa) << 3)];              \
        h##P_##10 = *(const bf16x8*)&V[pc + (((4 + quad) ^ sa) << 3)];        \
        g##P_##11 = *(const bf16x8*)&V[pd + ((quad ^ sb) << 3)];              \
        h##P_##11 = *(const bf16x8*)&V[pd + (((4 + quad) ^ sb) << 3)];        \
        if (w##P_##0 != 0.0f && !(iy0 && ix0)) {                              \
            const bf16_t* p = xb + (size_t)(cy0 * WW + cx0) * CC + cb;        \
            g##P_##00 = *(const bf16x8*)p;                                    \
            h##P_##00 = *(const bf16x8*)(p + 32);                             \
        }                                                                     \
        if (w##P_##1 != 0.0f && !(iy0 && ix1)) {                              \
            const bf16_t* p = xb + (size_t)(cy0 * WW + cx1) * CC + cb;        \
            g##P_##01 = *(const bf16x8*)p;                                    \
            h##P_##01 = *(const bf16x8*)(p + 32);                             \
        }                                                                     \
        if (w##P_##2 != 0.0f && !(iy1 && ix0)) {                              \
            const bf16_t* p = xb + (size_t)(cy1 * WW + cx0) * CC + cb;        \
            g##P_##10 = *(const bf16x8*)p;                                    \
            h##P_##10 = *(const bf16x8*)(p + 32);                             \
        }                                                                     \
        if (w##P_##3 != 0.0f && !(iy1 && ix1)) {                              \
            const bf16_t* p = xb + (size_t)(cy1 * WW + cx1) * CC + cb;        \
            g##P_##11 = *(const bf16x8*)p;                                    \
            h##P_##11 = *(const bf16x8*)(p + 32);                             \
        }                                                                     \
    }

#define BLEND(P_)                                                             \
    {                                                                         \
        _Pragma("unroll") for (int i = 0; i < 8; ++i) {                       \
            float v = w##P_##0 * (float)g##P_##00[i] +                        \
                      w##P_##1 * (float)g##P_##01[i] +                        \
                      w##P_##2 * (float)g##P_##10[i] +                        \
                      w##P_##3 * (float)g##P_##11[i];                         \
            af0[i] = (bf16_t)v;                                               \
        }                                                                     \
        _Pragma("unroll") for (int i = 0; i < 8; ++i) {                       \
            float v = w##P_##0 * (float)h##P_##00[i] +                        \
                      w##P_##1 * (float)h##P_##01[i] +                        \
                      w##P_##2 * (float)h##P_##10[i] +                        \
                      w##P_##3 * (float)h##P_##11[i];                         \
            af1[i] = (bf16_t)v;                                               \
        }                                                                     \
    }

#define MFMAS(k_)                                                             \
    {                                                                         \
        _Pragma("unroll") for (int nt = 0; nt < 4; ++nt) {                    \
            bf16x8 bfg = wf[((k_) * 8 + nt) * 64 + lane];                     \
            acc[nt] = __builtin_amdgcn_mfma_f32_16x16x32_bf16(                \
                af0, bfg, acc[nt], 0, 0, 0);                                  \
        }                                                                     \
        _Pragma("unroll") for (int nt = 0; nt < 4; ++nt) {                    \
            bf16x8 bfg = wf[((k_) * 8 + 4 + nt) * 64 + lane];                 \
            acc[nt] = __builtin_amdgcn_mfma_f32_16x16x32_bf16(                \
                af1, bfg, acc[nt], 0, 0, 0);                                  \
        }                                                                     \
    }

// BODY(k): issue tap k+1's gathers into the other set, roll scalars k+2 into
// this set's slots, pin with sched_barrier, then blend+MFMA tap k.
#define BODY(k_, P_, Q_)                                                      \
    {                                                                         \
        if ((k_) + 1 < KK) ISSUE((k_) + 1, Q_);                               \
        LOADS((k_) + 2, P_);                                                  \
        __builtin_amdgcn_sched_barrier(0);                                    \
        BLEND(P_);                                                            \
        MFMAS(k_);                                                            \
    }

    LOADS(0, A)
    LOADS(1, B)
    ISSUE(0, A);

    BODY(0, A, B)
    BODY(1, B, A)
    BODY(2, A, B)
    BODY(3, B, A)
    BODY(4, A, B)
    BODY(5, B, A)
    BODY(6, A, B)
    BODY(7, B, A)
    BODY(8, A, B)

#undef BODY
#undef MFMAS
#undef BLEND
#undef ISSUE
#undef LOADS

    // ---- epilogue: D[row=quad*4+reg][col]; row -> pixel m, col -> output ---
    // m = quad*4+reg: out row r0+2wv+(quad>>1), cols c0+(quad&1)*4 .. +3.
#pragma unroll
    for (int nt = 0; nt < 4; ++nt) {
        int o = nt * 16 + col;
        float bv = bias[o];
        f32x4 r = acc[nt];
        r.x += bv; r.y += bv; r.z += bv; r.w += bv;
        float* dst = out + (size_t)(b * OO + o) * HW +
                     (r0 + 2 * wv + (quad >> 1)) * WW + c0 + (quad & 1) * 4;
        *(f32x4*)dst = r;  // 4 consecutive pixels, 16B aligned
    }
}

extern "C" void kernel_launch(void* const* d_in, const int* in_sizes, int n_in,
                              void* d_out, int out_size, void* d_ws,
                              size_t ws_size, hipStream_t stream) {
    const float* x      = (const float*)d_in[0];
    const float* offset = (const float*)d_in[1];
    const float* mask   = (const float*)d_in[2];
    const float* weight = (const float*)d_in[3];
    const float* bias   = (const float*)d_in[4];
    float* out = (float*)d_out;

    bf16_t* xt  = (bf16_t*)d_ws;                       // 4*16384*64*2 = 8 MB
    bf16_t* wfr = (bf16_t*)((char*)d_ws + (size_t)BB * HW * CC * 2);  // 72 KB

    int nwf_blocks = (OO * CC * KK + 255) / 256;       // 144
    prep_kernel<<<BB * 256 + nwf_blocks, 256, 0, stream>>>(x, xt, weight, wfr);

    deform_conv_mfma<<<BB * (HW / 64), 256, 0, stream>>>(
        xt, offset, mask, (const bf16x8*)wfr, bias, out);
}

// Round 13
// 102.543 us; speedup vs baseline: 1.0514x; 1.0106x over previous
//
#include <hip/hip_runtime.h>

// Modulated deformable conv2d, fp32 in/out, bf16 MFMA core.
// B=4, C=64, H=W=128, O=64, K=3x3, stride=1, pad=1, dil=1, og=1, groups=1.
//
// Round 18: eliminate prep + xt (8 MB HBM write + read + serial launch) by
// staging each block's 16x16 window DIRECTLY from NCHW fp32 inside main --
// done right this time (r12's 53 us failure was 64 scalar same-bank
// ds_write_b16/thread + poor load economy):
//  - thread t stages window pixel t: 64 scalar fp32 loads (fixed channel
//    per instr -> lanes read consecutive addresses, fully coalesced),
//    packed into 8x ds_write_b128.
//  - V layout pitch 144B (72 bf16/px): slot(chunk,px) = (chunk+px)&7 --
//    pitch-based bank skew replaces the XOR swizzle (same conflict stats
//    for gather reads, conflict-light staging writes). h-slot = g-slot^4.
//  - fallback reads NCHW fp32 (r12's proven code). Bilinear/epilogue/wf/
//    XCD swizzle = r15 verbatim. LDS 36 KB -> 4 blocks/CU unchanged.
// Fragment layouts (m89/m120-verified): A[m=lane&15][k=quad*8+j],
// B[k=quad*8+j][n=lane&15], D[row=quad*4+reg][col=lane&15].

#define BB 4
#define CC 64
#define HH 128
#define WW 128
#define OO 64
#define KHW 3
#define KK 9
#define HW (HH * WW)

typedef __bf16 bf16_t;
typedef bf16_t bf16x8 __attribute__((ext_vector_type(8)));
typedef float f32x4 __attribute__((ext_vector_type(4)));

// ---- weight [O][C][3][3] fp32 -> B-fragment order bf16 ----
// wf element index: ((tap*2+q)*4+nt)*64*8 + lane*8 + j
//   holds W[o = nt*16 + (lane&15)][c = q*32 + (lane>>4)*8 + j][tap]
__global__ void wfrag_kernel(const float* __restrict__ w,
                             bf16_t* __restrict__ wf) {
    int i = blockIdx.x * blockDim.x + threadIdx.x;
    if (i >= OO * CC * KK) return;
    int j    = i & 7;
    int lane = (i >> 3) & 63;
    int nt   = (i >> 9) & 3;
    int q    = (i >> 11) & 1;
    int k    = i >> 12;
    int o = nt * 16 + (lane & 15);
    int c = q * 32 + ((lane >> 4) << 3) + j;
    wf[i] = (bf16_t)w[(o * CC + c) * KK + k];
}

__global__ __launch_bounds__(256, 4) void deform_conv_mfma(
    const float* __restrict__ x, const float* __restrict__ offset,
    const float* __restrict__ mask, const bf16x8* __restrict__ wf,
    const float* __restrict__ bias, float* __restrict__ out) {
    const int t    = threadIdx.x;
    // XCD-aware bijective swizzle: grid = 1024 = 8 * 128.
    const int wg   = (blockIdx.x & 7) * ((BB * 256) >> 3) + (blockIdx.x >> 3);
    const int b    = wg >> 8;
    const int ti   = wg & 255;                 // tile id: 16x16 tiles of 8x8
    const int r0   = ((ti >> 4) << 3);         // tile top row
    const int c0   = ((ti & 15) << 3);         // tile left col
    const int lane = t & 63;
    const int wv   = t >> 6;                   // wave: rows 2wv, 2wv+1
    const int col  = lane & 15;                // A-row m == pixel in wave
    const int quad = lane >> 4;
    const int prow = r0 + 2 * wv + (col >> 3); // this lane's pixel row
    const int pcol = c0 + (col & 7);
    const int rem  = prow * WW + pcol;
    const int wy0  = r0 - 4;                   // window origin (16x16 px)
    const int wx0  = c0 - 4;
    const int cbh  = quad << 3;                // fallback channel base (g)

    __shared__ bf16_t V[256 * 72];             // 36 KB, pitch-skewed window

    const float* xb   = x + (size_t)b * CC * HW;
    const float* offp = offset + (size_t)b * (2 * KK) * HW + rem;
    const float* mp   = mask + (size_t)b * KK * HW + rem;

    // ---- stage 16x16-px window straight from NCHW fp32 ----
    // thread t <-> window pixel t. 64 scalar loads, fixed channel per
    // instr -> lanes read consecutive floats (coalesced). 8 b128 writes.
    {
        const int i  = t >> 4;                 // window row 0..15
        const int j  = t & 15;                 // window col 0..15
        const int cy = min(max(wy0 + i, 0), HH - 1);
        const int cx = min(max(wx0 + j, 0), WW - 1);
        const float* src = xb + cy * WW + cx;
        bf16_t* dst = &V[t * 72];
#pragma unroll
        for (int s = 0; s < 8; ++s) {
            bf16x8 v;
#pragma unroll
            for (int e = 0; e < 8; ++e) v[e] = (bf16_t)src[(s * 8 + e) * HW];
            *(bf16x8*)(dst + (((s + t) & 7) << 3)) = v;  // skewed slot
        }
    }
    __syncthreads();

    f32x4 acc[4];
#pragma unroll
    for (int nt = 0; nt < 4; ++nt) acc[nt] = (f32x4){0.f, 0.f, 0.f, 0.f};

    float offy = offp[0];
    float offx = offp[HW];
    float mm   = mp[0];

#pragma unroll
    for (int k = 0; k < KK; ++k) {
        float n_offy = 0.f, n_offx = 0.f, n_mm = 0.f;
        if (k < KK - 1) {
            n_offy = offp[(2 * k + 2) * HW];
            n_offx = offp[(2 * k + 3) * HW];
            n_mm   = mp[(k + 1) * HW];
        }

        // ---- bilinear setup (exact reference semantics) ----
        float py = offy + (float)(k / KHW) + (float)(prow - 1);
        float px = offx + (float)(k % KHW) + (float)(pcol - 1);
        float fy0 = floorf(py), fx0 = floorf(px);
        float ly = py - fy0, lx = px - fx0;
        int y0 = (int)fy0, x0 = (int)fx0;
        int y1 = y0 + 1, x1 = x0 + 1;
        bool vy0 = (y0 >= 0) && (y0 < HH), vy1 = (y1 >= 0) && (y1 < HH);
        bool vx0 = (x0 >= 0) && (x0 < WW), vx1 = (x1 >= 0) && (x1 < WW);
        int cy0 = min(max(y0, 0), HH - 1), cy1 = min(max(y1, 0), HH - 1);
        int cx0 = min(max(x0, 0), WW - 1), cx1 = min(max(x1, 0), WW - 1);
        float w0 = (vy0 && vx0) ? mm * (1.0f - ly) * (1.0f - lx) : 0.0f;
        float w1 = (vy0 && vx1) ? mm * (1.0f - ly) * lx : 0.0f;
        float w2 = (vy1 && vx0) ? mm * ly * (1.0f - lx) : 0.0f;
        float w3 = (vy1 && vx1) ? mm * ly * lx : 0.0f;

        // ---- window-relative corner coords ----
        int uy0 = y0 - wy0, ux0 = x0 - wx0;
        int uy1 = uy0 + 1,  ux1 = ux0 + 1;
        bool iy0 = (unsigned)uy0 < 16u, iy1 = (unsigned)uy1 < 16u;
        bool ix0 = (unsigned)ux0 < 16u, ix1 = (unsigned)ux1 < 16u;
        int qy0 = min(max(uy0, 0), 15), qy1 = min(max(uy1, 0), 15);
        int qx0 = min(max(ux0, 0), 15), qx1 = min(max(ux1, 0), 15);
        int pa = qy0 * 16 + qx0, pb = qy0 * 16 + qx1;   // corner pixel ids
        int pc = qy1 * 16 + qx0, pd = qy1 * 16 + qx1;
        int sa = (quad + pa) & 7, sb = (quad + pb) & 7; // g-slots (h = ^4)
        int sc = (quad + pc) & 7, sd = (quad + pd) & 7;

        // ---- LDS gathers: g = chunk quad, h = chunk 4+quad ----
        bf16x8 g00 = *(const bf16x8*)&V[pa * 72 + (sa << 3)];
        bf16x8 h00 = *(const bf16x8*)&V[pa * 72 + ((sa ^ 4) << 3)];
        bf16x8 g01 = *(const bf16x8*)&V[pb * 72 + (sb << 3)];
        bf16x8 h01 = *(const bf16x8*)&V[pb * 72 + ((sb ^ 4) << 3)];
        bf16x8 g10 = *(const bf16x8*)&V[pc * 72 + (sc << 3)];
        bf16x8 h10 = *(const bf16x8*)&V[pc * 72 + ((sc ^ 4) << 3)];
        bf16x8 g11 = *(const bf16x8*)&V[pd * 72 + (sd << 3)];
        bf16x8 h11 = *(const bf16x8*)&V[pd * 72 + ((sd ^ 4) << 3)];

        // ---- rare out-of-window fallback (exec-masked, NCHW fp32 source) --
        if (w0 != 0.0f && !(iy0 && ix0)) {
            const float* p = xb + (size_t)cbh * HW + cy0 * WW + cx0;
#pragma unroll
            for (int i = 0; i < 8; ++i) {
                g00[i] = (bf16_t)p[i * HW];
                h00[i] = (bf16_t)p[(32 + i) * HW];
            }
        }
        if (w1 != 0.0f && !(iy0 && ix1)) {
            const float* p = xb + (size_t)cbh * HW + cy0 * WW + cx1;
#pragma unroll
            for (int i = 0; i < 8; ++i) {
                g01[i] = (bf16_t)p[i * HW];
                h01[i] = (bf16_t)p[(32 + i) * HW];
            }
        }
        if (w2 != 0.0f && !(iy1 && ix0)) {
            const float* p = xb + (size_t)cbh * HW + cy1 * WW + cx0;
#pragma unroll
            for (int i = 0; i < 8; ++i) {
                g10[i] = (bf16_t)p[i * HW];
                h10[i] = (bf16_t)p[(32 + i) * HW];
            }
        }
        if (w3 != 0.0f && !(iy1 && ix1)) {
            const float* p = xb + (size_t)cbh * HW + cy1 * WW + cx1;
#pragma unroll
            for (int i = 0; i < 8; ++i) {
                g11[i] = (bf16_t)p[i * HW];
                h11[i] = (bf16_t)p[(32 + i) * HW];
            }
        }

        // ---- blend -> A fragments ----
        bf16x8 af0, af1;
#pragma unroll
        for (int i = 0; i < 8; ++i) {
            float v = w0 * (float)g00[i] + w1 * (float)g01[i] +
                      w2 * (float)g10[i] + w3 * (float)g11[i];
            af0[i] = (bf16_t)v;
        }
#pragma unroll
        for (int i = 0; i < 8; ++i) {
            float v = w0 * (float)h00[i] + w1 * (float)h01[i] +
                      w2 * (float)h10[i] + w3 * (float)h11[i];
            af1[i] = (bf16_t)v;
        }

        // ---- MFMA: 16 pixels x 64 outputs, K=64 (one tap) ----
#pragma unroll
        for (int nt = 0; nt < 4; ++nt) {
            bf16x8 bfg = wf[(k * 8 + nt) * 64 + lane];
            acc[nt] = __builtin_amdgcn_mfma_f32_16x16x32_bf16(
                af0, bfg, acc[nt], 0, 0, 0);
        }
#pragma unroll
        for (int nt = 0; nt < 4; ++nt) {
            bf16x8 bfg = wf[(k * 8 + 4 + nt) * 64 + lane];
            acc[nt] = __builtin_amdgcn_mfma_f32_16x16x32_bf16(
                af1, bfg, acc[nt], 0, 0, 0);
        }

        offy = n_offy;
        offx = n_offx;
        mm   = n_mm;
    }

    // ---- epilogue: D[row=quad*4+reg][col]; row -> pixel m, col -> output ---
    // m = quad*4+reg: out row r0+2wv+(quad>>1), cols c0+(quad&1)*4 .. +3.
#pragma unroll
    for (int nt = 0; nt < 4; ++nt) {
        int o = nt * 16 + col;
        float bv = bias[o];
        f32x4 r = acc[nt];
        r.x += bv; r.y += bv; r.z += bv; r.w += bv;
        float* dst = out + (size_t)(b * OO + o) * HW +
                     (r0 + 2 * wv + (quad >> 1)) * WW + c0 + (quad & 1) * 4;
        *(f32x4*)dst = r;  // 4 consecutive pixels, 16B aligned
    }
}

extern "C" void kernel_launch(void* const* d_in, const int* in_sizes, int n_in,
                              void* d_out, int out_size, void* d_ws,
                              size_t ws_size, hipStream_t stream) {
    const float* x      = (const float*)d_in[0];
    const float* offset = (const float*)d_in[1];
    const float* mask   = (const float*)d_in[2];
    const float* weight = (const float*)d_in[3];
    const float* bias   = (const float*)d_in[4];
    float* out = (float*)d_out;

    bf16_t* wfr = (bf16_t*)d_ws;                       // 72 KB

    int nw = OO * CC * KK;  // 36864
    wfrag_kernel<<<(nw + 255) / 256, 256, 0, stream>>>(weight, wfr);

    deform_conv_mfma<<<BB * (HW / 64), 256, 0, stream>>>(
        x, offset, mask, (const bf16x8*)wfr, bias, out);
}